// Round 15
// baseline (33.249 us; speedup 1.0000x reference)
//
#include <hip/hip_runtime.h>

#define NODES 14
#define IN_F 24
#define HID1 32
#define HID2 64
#define OUT_F 24
#define SLOPE 0.2f

// u-vector layout in d_ws: us1[48] ud1[48] us2[64] ud2[64]  (224 floats)
#define U_US1 0
#define U_UD1 48
#define U_US2 96
#define U_UD2 160

#define GPB 4           // graphs (= waves) per block
#define PHASE_FENCE() __builtin_amdgcn_sched_barrier(0)

// ---- kernel 1: precompute u = W @ a  (graph-invariant, once) ----
__global__ __launch_bounds__(256) void compute_uvecs(
    const float* __restrict__ W1, const float* __restrict__ a_src1,
    const float* __restrict__ a_dst1,
    const float* __restrict__ W2, const float* __restrict__ a_src2,
    const float* __restrict__ a_dst2, float* __restrict__ u)
{
  const int tid = threadIdx.x;
  if (tid < 96) {
    const int sd = (tid >= 48), r = tid - sd * 48;
    const int h = (r >= IN_F), k = r - h * IN_F;
    const float* av = sd ? a_dst1 : a_src1;
    float s = 0.f;
#pragma unroll
    for (int f = 0; f < HID1; ++f)
      s += W1[k * 64 + h * HID1 + f] * av[h * HID1 + f];
    u[(sd ? U_UD1 : U_US1) + h * IN_F + k] = s;
  } else if (tid < 224) {
    const int j = tid - 96;
    const int sd = (j >= 64), r = j - sd * 64;
    const int h = (r >= HID1), k = r - h * HID1;
    const float* av = sd ? a_dst2 : a_src2;
    float s = 0.f;
#pragma unroll
    for (int f = 0; f < HID2; ++f)
      s += W2[k * 128 + h * HID2 + f] * av[h * HID2 + f];
    u[(sd ? U_UD2 : U_US2) + h * HID1 + k] = s;
  }
}

// ---- kernel 2: fused GNN+MLP — ONE WAVE PER GRAPH, ZERO BARRIERS ----
// R15: every producer->consumer edge is wave-internal (lgkmcnt ordering,
// inserted by the compiler), so no __syncthreads exist. 4 independent
// waves per 256-thread block share nothing but the LDS allocation
// (disjoint per-wave arenas). GEMM1: col=lane; agg1: head-combine via one
// shfl_xor(32); GEMM2: lane owns cols {lane, 64+lane} so agg2 is
// lane-local for both heads; logits/softmax on 56/28 lanes. x reads go
// through an SGPR pointer (readfirstlane) -> s_load on the SMEM pipe.
__global__ __launch_bounds__(64 * GPB) void gnn_fused(
    const float* __restrict__ x, const float* __restrict__ y,
    const float* __restrict__ W1, const float* __restrict__ b1,
    const float* __restrict__ W2, const float* __restrict__ b2,
    const float* __restrict__ Wf1, const float* __restrict__ bf1,
    const float* __restrict__ Wf2, const float* __restrict__ bf2,
    const float* __restrict__ uvec,
    float* __restrict__ out, int ngraphs)
{
  const int tid  = threadIdx.x;
  const int lane = tid & 63;
  const int wv   = tid >> 6;
  const int gu   = __builtin_amdgcn_readfirstlane(blockIdx.x * GPB + wv);
  if (gu >= ngraphs) return;     // whole-wave exit; no barriers -> safe

  __shared__ __align__(16) float h1s[GPB][NODES * 32];  // 448/graph
  __shared__ __align__(16) float h2s[GPB][NODES * 64];  // 896/graph
  __shared__ __align__(16) float wt[GPB][28 * 16];      // [(j*2+h)][i]
  __shared__ __align__(16) float als[GPB][32];          // [h*16+n]
  __shared__ __align__(16) float ald[GPB][32];
  __shared__ __align__(16) float hhs[GPB][112];

  const float* xg = x + (size_t)gu * (NODES * IN_F);    // SGPR base

  // ---- y-copy (independent; hides under compute) ----
  {
    const float4* y4 = (const float4*)(y + (size_t)gu * (NODES * OUT_F));
    float4* o4 = (float4*)(out + (size_t)NODES * ngraphs * OUT_F
                               + (size_t)gu * (NODES * OUT_F));
    for (int i = lane; i < (NODES * OUT_F) / 4; i += 64) o4[i] = y4[i];
  }

  // ---- GEMM1: col = lane (scalar x reads via SGPR base) ----
  float xcol[NODES];
  {
    float w1r[IN_F];
#pragma unroll
    for (int k = 0; k < IN_F; ++k) w1r[k] = W1[k * 64 + lane];
#pragma unroll 2
    for (int n = 0; n < NODES; ++n) {
      float acc = 0.f;
#pragma unroll
      for (int k = 0; k < IN_F; ++k) acc += xg[n * IN_F + k] * w1r[k];
      xcol[n] = acc;
    }
  }
  PHASE_FENCE();

  // ---- logits1 (56 lanes): al[n,h,sd] = x[n,:].u1[h,sd,:] ----
  if (lane < 56) {
    const int n = lane >> 2, h = (lane >> 1) & 1, sd = lane & 1;
    const float* uu = uvec + (sd ? U_UD1 : U_US1) + h * IN_F;
    float s = 0.f;
#pragma unroll
    for (int k4 = 0; k4 < 6; ++k4) {
      const float4 xv = *(const float4*)&xg[n * IN_F + k4 * 4];
      const float4 uv = *(const float4*)&uu[k4 * 4];
      s += xv.x * uv.x + xv.y * uv.y + xv.z * uv.z + xv.w * uv.w;
    }
    (sd ? ald : als)[wv][h * 16 + n] = s;
  }
  // ---- softmax1 (28 lanes, wave-internal ordering) ----
  if (lane < NODES * 2) {
    const int j = lane >> 1, h = lane & 1;
    const float ad = ald[wv][h * 16 + j];
    const float4 A0 = *(const float4*)&als[wv][h * 16 + 0];
    const float4 A1 = *(const float4*)&als[wv][h * 16 + 4];
    const float4 A2 = *(const float4*)&als[wv][h * 16 + 8];
    const float2 A3 = *(const float2*)&als[wv][h * 16 + 12];
    float a[NODES] = {A0.x, A0.y, A0.z, A0.w, A1.x, A1.y, A1.z, A1.w,
                      A2.x, A2.y, A2.z, A2.w, A3.x, A3.y};
    float m = -1e30f;
#pragma unroll
    for (int i = 0; i < NODES; ++i) {
      float v = a[i] + ad;
      v = v > 0.f ? v : SLOPE * v;
      a[i] = v; m = fmaxf(m, v);
    }
    float den = 0.f;
#pragma unroll
    for (int i = 0; i < NODES; ++i) { a[i] = __expf(a[i] - m); den += a[i]; }
    const float r = 1.f / den;
    float* wr = &wt[wv][(j * 2 + h) * 16];
    *(float4*)&wr[0]  = make_float4(a[0]*r,  a[1]*r,  a[2]*r,  a[3]*r);
    *(float4*)&wr[4]  = make_float4(a[4]*r,  a[5]*r,  a[6]*r,  a[7]*r);
    *(float4*)&wr[8]  = make_float4(a[8]*r,  a[9]*r,  a[10]*r, a[11]*r);
    *(float2*)&wr[12] = make_float2(a[12]*r, a[13]*r);
  }
  PHASE_FENCE();

  // ---- agg1: all lanes; head = lane>>5, feat = lane&31; shfl combine ----
  {
    const int h = lane >> 5, f5 = lane & 31;
    const float bb = b1[f5];
#pragma unroll 2
    for (int n = 0; n < NODES; ++n) {
      const float* wr = &wt[wv][(n * 2 + h) * 16];
      const float4 w0 = *(const float4*)&wr[0];
      const float4 w1 = *(const float4*)&wr[4];
      const float4 w2 = *(const float4*)&wr[8];
      const float2 w3 = *(const float2*)&wr[12];
      float o = w0.x*xcol[0] + w0.y*xcol[1] + w0.z*xcol[2] + w0.w*xcol[3]
              + w1.x*xcol[4] + w1.y*xcol[5] + w1.z*xcol[6] + w1.w*xcol[7]
              + w2.x*xcol[8] + w2.y*xcol[9] + w2.z*xcol[10] + w2.w*xcol[11]
              + w3.x*xcol[12] + w3.y*xcol[13];
      const float oo = __shfl_xor(o, 32);
      if (h == 0) {
        const float v = 0.5f * (o + oo) + bb;
        h1s[wv][n * 32 + f5] = v > 0.f ? v : expm1f(v);
      }
    }
  }
  PHASE_FENCE();

  // ---- GEMM2: lane owns cols {lane, 64+lane}; two 16-k chunks ----
  float acc0[NODES], acc1[NODES];
#pragma unroll
  for (int n = 0; n < NODES; ++n) { acc0[n] = 0.f; acc1[n] = 0.f; }
#pragma unroll
  for (int c = 0; c < 2; ++c) {
    float w2a[16], w2b[16];
#pragma unroll
    for (int j = 0; j < 16; ++j) {
      w2a[j] = W2[(c * 16 + j) * 128 + lane];
      w2b[j] = W2[(c * 16 + j) * 128 + 64 + lane];
    }
#pragma unroll 2
    for (int n = 0; n < NODES; ++n) {
      const float4 v0 = *(const float4*)&h1s[wv][n * 32 + c * 16 + 0];
      const float4 v1 = *(const float4*)&h1s[wv][n * 32 + c * 16 + 4];
      const float4 v2 = *(const float4*)&h1s[wv][n * 32 + c * 16 + 8];
      const float4 v3 = *(const float4*)&h1s[wv][n * 32 + c * 16 + 12];
      acc0[n] += v0.x*w2a[0] + v0.y*w2a[1] + v0.z*w2a[2] + v0.w*w2a[3]
               + v1.x*w2a[4] + v1.y*w2a[5] + v1.z*w2a[6] + v1.w*w2a[7]
               + v2.x*w2a[8] + v2.y*w2a[9] + v2.z*w2a[10] + v2.w*w2a[11]
               + v3.x*w2a[12] + v3.y*w2a[13] + v3.z*w2a[14] + v3.w*w2a[15];
      acc1[n] += v0.x*w2b[0] + v0.y*w2b[1] + v0.z*w2b[2] + v0.w*w2b[3]
               + v1.x*w2b[4] + v1.y*w2b[5] + v1.z*w2b[6] + v1.w*w2b[7]
               + v2.x*w2b[8] + v2.y*w2b[9] + v2.z*w2b[10] + v2.w*w2b[11]
               + v3.x*w2b[12] + v3.y*w2b[13] + v3.z*w2b[14] + v3.w*w2b[15];
    }
    PHASE_FENCE();
  }

  // ---- logits2 (56 lanes): h1 row . u2 row ----
  if (lane < 56) {
    const int n = lane >> 2, h = (lane >> 1) & 1, sd = lane & 1;
    const float* uu = uvec + (sd ? U_UD2 : U_US2) + h * HID1;
    float s = 0.f;
#pragma unroll
    for (int k4 = 0; k4 < 8; ++k4) {
      const float4 hv = *(const float4*)&h1s[wv][n * 32 + k4 * 4];
      const float4 uv = *(const float4*)&uu[k4 * 4];
      s += hv.x * uv.x + hv.y * uv.y + hv.z * uv.z + hv.w * uv.w;
    }
    (sd ? ald : als)[wv][h * 16 + n] = s;
  }
  // ---- softmax2 (28 lanes) ----
  if (lane < NODES * 2) {
    const int j = lane >> 1, h = lane & 1;
    const float ad = ald[wv][h * 16 + j];
    const float4 A0 = *(const float4*)&als[wv][h * 16 + 0];
    const float4 A1 = *(const float4*)&als[wv][h * 16 + 4];
    const float4 A2 = *(const float4*)&als[wv][h * 16 + 8];
    const float2 A3 = *(const float2*)&als[wv][h * 16 + 12];
    float a[NODES] = {A0.x, A0.y, A0.z, A0.w, A1.x, A1.y, A1.z, A1.w,
                      A2.x, A2.y, A2.z, A2.w, A3.x, A3.y};
    float m = -1e30f;
#pragma unroll
    for (int i = 0; i < NODES; ++i) {
      float v = a[i] + ad;
      v = v > 0.f ? v : SLOPE * v;
      a[i] = v; m = fmaxf(m, v);
    }
    float den = 0.f;
#pragma unroll
    for (int i = 0; i < NODES; ++i) { a[i] = __expf(a[i] - m); den += a[i]; }
    const float r = 1.f / den;
    float* wr = &wt[wv][(j * 2 + h) * 16];
    *(float4*)&wr[0]  = make_float4(a[0]*r,  a[1]*r,  a[2]*r,  a[3]*r);
    *(float4*)&wr[4]  = make_float4(a[4]*r,  a[5]*r,  a[6]*r,  a[7]*r);
    *(float4*)&wr[8]  = make_float4(a[8]*r,  a[9]*r,  a[10]*r, a[11]*r);
    *(float2*)&wr[12] = make_float2(a[12]*r, a[13]*r);
  }
  PHASE_FENCE();

  // ---- agg2: lane-local for both heads (lane holds cols lane, 64+lane) ----
  {
    const float bb = b2[lane];
#pragma unroll 2
    for (int n = 0; n < NODES; ++n) {
      const float* wr0 = &wt[wv][(n * 2 + 0) * 16];
      const float* wr1 = &wt[wv][(n * 2 + 1) * 16];
      const float4 p0 = *(const float4*)&wr0[0];
      const float4 p1 = *(const float4*)&wr0[4];
      const float4 p2 = *(const float4*)&wr0[8];
      const float2 p3 = *(const float2*)&wr0[12];
      const float4 q0 = *(const float4*)&wr1[0];
      const float4 q1 = *(const float4*)&wr1[4];
      const float4 q2 = *(const float4*)&wr1[8];
      const float2 q3 = *(const float2*)&wr1[12];
      const float o0 = p0.x*acc0[0] + p0.y*acc0[1] + p0.z*acc0[2] + p0.w*acc0[3]
                     + p1.x*acc0[4] + p1.y*acc0[5] + p1.z*acc0[6] + p1.w*acc0[7]
                     + p2.x*acc0[8] + p2.y*acc0[9] + p2.z*acc0[10] + p2.w*acc0[11]
                     + p3.x*acc0[12] + p3.y*acc0[13];
      const float o1 = q0.x*acc1[0] + q0.y*acc1[1] + q0.z*acc1[2] + q0.w*acc1[3]
                     + q1.x*acc1[4] + q1.y*acc1[5] + q1.z*acc1[6] + q1.w*acc1[7]
                     + q2.x*acc1[8] + q2.y*acc1[9] + q2.z*acc1[10] + q2.w*acc1[11]
                     + q3.x*acc1[12] + q3.y*acc1[13];
      h2s[wv][n * 64 + lane] = 0.5f * (o0 + o1) + bb;
    }
  }
  PHASE_FENCE();

  // ---- MLP1 (112 items, 2 per lane max; float4 h2 broadcasts) ----
  for (int idx = lane; idx < NODES * 8; idx += 64) {
    const int k = idx >> 3, e = idx & 7;
    float acc = bf1[k * 8 + e];
#pragma unroll
    for (int f4 = 0; f4 < 16; ++f4) {
      const float4 hv = *(const float4*)&h2s[wv][k * 64 + f4 * 4];
      acc += hv.x * Wf1[(k * HID2 + f4 * 4 + 0) * 8 + e]
           + hv.y * Wf1[(k * HID2 + f4 * 4 + 1) * 8 + e]
           + hv.z * Wf1[(k * HID2 + f4 * 4 + 2) * 8 + e]
           + hv.w * Wf1[(k * HID2 + f4 * 4 + 3) * 8 + e];
    }
    hhs[wv][idx] = fmaxf(acc, 0.f);
  }
  PHASE_FENCE();

  // ---- MLP2 (336 outputs; float4 hhs broadcasts) ----
  for (int idx = lane; idx < NODES * OUT_F; idx += 64) {
    const int k = idx / OUT_F, o = idx - k * OUT_F;
    const float4 h0 = *(const float4*)&hhs[wv][k * 8];
    const float4 h1 = *(const float4*)&hhs[wv][k * 8 + 4];
    float acc = bf2[k * OUT_F + o]
              + h0.x * Wf2[(k * 8 + 0) * OUT_F + o]
              + h0.y * Wf2[(k * 8 + 1) * OUT_F + o]
              + h0.z * Wf2[(k * 8 + 2) * OUT_F + o]
              + h0.w * Wf2[(k * 8 + 3) * OUT_F + o]
              + h1.x * Wf2[(k * 8 + 4) * OUT_F + o]
              + h1.y * Wf2[(k * 8 + 5) * OUT_F + o]
              + h1.z * Wf2[(k * 8 + 6) * OUT_F + o]
              + h1.w * Wf2[(k * 8 + 7) * OUT_F + o];
    out[(size_t)k * ngraphs * OUT_F + (size_t)gu * OUT_F + o] =
        1.f / (1.f + __expf(-acc));
  }
}

extern "C" void kernel_launch(void* const* d_in, const int* in_sizes, int n_in,
                              void* d_out, int out_size, void* d_ws, size_t ws_size,
                              hipStream_t stream) {
  const float* x      = (const float*)d_in[0];
  const float* y      = (const float*)d_in[1];
  // d_in[2] = edge_index, d_in[3] = batch : structure fixed, unused
  const float* W1     = (const float*)d_in[4];
  const float* a_src1 = (const float*)d_in[5];
  const float* a_dst1 = (const float*)d_in[6];
  const float* b1     = (const float*)d_in[7];
  const float* W2     = (const float*)d_in[8];
  const float* a_src2 = (const float*)d_in[9];
  const float* a_dst2 = (const float*)d_in[10];
  const float* b2     = (const float*)d_in[11];
  const float* Wf1    = (const float*)d_in[12];
  const float* bf1    = (const float*)d_in[13];
  const float* Wf2    = (const float*)d_in[14];
  const float* bf2    = (const float*)d_in[15];
  float* out = (float*)d_out;
  float* u   = (float*)d_ws;

  const int nnodes  = in_sizes[0] / IN_F;
  const int ngraphs = nnodes / NODES;
  const int nblocks = (ngraphs + GPB - 1) / GPB;

  hipLaunchKernelGGL(compute_uvecs, dim3(1), dim3(256), 0, stream,
                     W1, a_src1, a_dst1, W2, a_src2, a_dst2, u);
  hipLaunchKernelGGL(gnn_fused, dim3(nblocks), dim3(64 * GPB), 0, stream,
                     x, y, W1, b1, W2, b2, Wf1, bf1, Wf2, bf2, u, out, ngraphs);
}

// Round 16
// 30.521 us; speedup vs baseline: 1.0894x; 1.0894x over previous
//
#include <hip/hip_runtime.h>

#define NODES 14
#define IN_F 24
#define HID1 32
#define HID2 64
#define OUT_F 24
#define SLOPE 0.2f

// u-vector layout in d_ws: us1[48] ud1[48] us2[64] ud2[64]  (224 floats)
#define U_US1 0
#define U_UD1 48
#define U_US2 96
#define U_UD2 160

#define GPB 4           // graphs (= waves) per block
#define H1_S 36         // h1 stride (float4-aligned, anti-alias padded)
#define H2_S 68         // h2 stride
#define WT_S 20         // wt row stride (80 B: rows spread across banks)
#define PHASE_FENCE() __builtin_amdgcn_sched_barrier(0)

// ---- kernel 1: precompute u = W @ a  (graph-invariant, once) ----
__global__ __launch_bounds__(256) void compute_uvecs(
    const float* __restrict__ W1, const float* __restrict__ a_src1,
    const float* __restrict__ a_dst1,
    const float* __restrict__ W2, const float* __restrict__ a_src2,
    const float* __restrict__ a_dst2, float* __restrict__ u)
{
  const int tid = threadIdx.x;
  if (tid < 96) {
    const int sd = (tid >= 48), r = tid - sd * 48;
    const int h = (r >= IN_F), k = r - h * IN_F;
    const float* av = sd ? a_dst1 : a_src1;
    float s = 0.f;
#pragma unroll
    for (int f = 0; f < HID1; ++f)
      s += W1[k * 64 + h * HID1 + f] * av[h * HID1 + f];
    u[(sd ? U_UD1 : U_US1) + h * IN_F + k] = s;
  } else if (tid < 224) {
    const int j = tid - 96;
    const int sd = (j >= 64), r = j - sd * 64;
    const int h = (r >= HID1), k = r - h * HID1;
    const float* av = sd ? a_dst2 : a_src2;
    float s = 0.f;
#pragma unroll
    for (int f = 0; f < HID2; ++f)
      s += W2[k * 128 + h * HID2 + f] * av[h * HID2 + f];
    u[(sd ? U_UD2 : U_US2) + h * HID1 + k] = s;
  }
}

// ---- kernel 2: fused GNN+MLP — one wave per graph, zero barriers ----
// R16 = R15 + (a) LDS stride padding (R15 dropped R12's padding: wt
// stride 16 = 14-way write conflicts, 901K SQ_LDS_BANK_CONFLICT) and
// (b) ALL W1/W2 loads hoisted to kernel top (88 VGPRs), pinned with one
// sched fence so ~600cy of global latency overlaps GEMM1 instead of
// serializing into the wave's barrier-free dependence chain.
__global__ __launch_bounds__(64 * GPB) void gnn_fused(
    const float* __restrict__ x, const float* __restrict__ y,
    const float* __restrict__ W1, const float* __restrict__ b1,
    const float* __restrict__ W2, const float* __restrict__ b2,
    const float* __restrict__ Wf1, const float* __restrict__ bf1,
    const float* __restrict__ Wf2, const float* __restrict__ bf2,
    const float* __restrict__ uvec,
    float* __restrict__ out, int ngraphs)
{
  const int tid  = threadIdx.x;
  const int lane = tid & 63;
  const int wv   = tid >> 6;
  const int gu   = __builtin_amdgcn_readfirstlane(blockIdx.x * GPB + wv);
  if (gu >= ngraphs) return;     // whole-wave exit; no barriers -> safe

  __shared__ __align__(16) float h1s[GPB][NODES * H1_S];
  __shared__ __align__(16) float h2s[GPB][NODES * H2_S];
  __shared__ __align__(16) float wt[GPB][28 * WT_S];
  __shared__ __align__(16) float als[GPB][32];          // [h*16+n]
  __shared__ __align__(16) float ald[GPB][32];
  __shared__ __align__(16) float hhs[GPB][112];

  const float* xg = x + (size_t)gu * (NODES * IN_F);    // SGPR base

  // ---- top prefetch: W1 col + BOTH W2 cols for this lane ----
  float w1r[IN_F];
#pragma unroll
  for (int k = 0; k < IN_F; ++k) w1r[k] = W1[k * 64 + lane];
  float w2r[64];
#pragma unroll
  for (int k = 0; k < HID1; ++k) {
    w2r[k]      = W2[k * 128 + lane];
    w2r[32 + k] = W2[k * 128 + 64 + lane];
  }
  PHASE_FENCE();   // pin loads at top (stop the scheduler sinking them)

  // ---- y-copy (independent; overlaps everything) ----
  {
    const float4* y4 = (const float4*)(y + (size_t)gu * (NODES * OUT_F));
    float4* o4 = (float4*)(out + (size_t)NODES * ngraphs * OUT_F
                               + (size_t)gu * (NODES * OUT_F));
    for (int i = lane; i < (NODES * OUT_F) / 4; i += 64) o4[i] = y4[i];
  }

  // ---- GEMM1: col = lane (scalar x broadcasts via SGPR base) ----
  float xcol[NODES];
#pragma unroll 2
  for (int n = 0; n < NODES; ++n) {
    float acc = 0.f;
#pragma unroll
    for (int k = 0; k < IN_F; ++k) acc += xg[n * IN_F + k] * w1r[k];
    xcol[n] = acc;
  }

  // ---- logits1 (56 lanes): al[n,h,sd] = x[n,:].u1[h,sd,:] ----
  if (lane < 56) {
    const int n = lane >> 2, h = (lane >> 1) & 1, sd = lane & 1;
    const float* uu = uvec + (sd ? U_UD1 : U_US1) + h * IN_F;
    float s = 0.f;
#pragma unroll
    for (int k4 = 0; k4 < 6; ++k4) {
      const float4 xv = *(const float4*)&xg[n * IN_F + k4 * 4];
      const float4 uv = *(const float4*)&uu[k4 * 4];
      s += xv.x * uv.x + xv.y * uv.y + xv.z * uv.z + xv.w * uv.w;
    }
    (sd ? ald : als)[wv][h * 16 + n] = s;
  }
  // ---- softmax1 (28 lanes, wave-internal LDS ordering) ----
  if (lane < NODES * 2) {
    const int j = lane >> 1, h = lane & 1;
    const float ad = ald[wv][h * 16 + j];
    const float4 A0 = *(const float4*)&als[wv][h * 16 + 0];
    const float4 A1 = *(const float4*)&als[wv][h * 16 + 4];
    const float4 A2 = *(const float4*)&als[wv][h * 16 + 8];
    const float2 A3 = *(const float2*)&als[wv][h * 16 + 12];
    float a[NODES] = {A0.x, A0.y, A0.z, A0.w, A1.x, A1.y, A1.z, A1.w,
                      A2.x, A2.y, A2.z, A2.w, A3.x, A3.y};
    float m = -1e30f;
#pragma unroll
    for (int i = 0; i < NODES; ++i) {
      float v = a[i] + ad;
      v = v > 0.f ? v : SLOPE * v;
      a[i] = v; m = fmaxf(m, v);
    }
    float den = 0.f;
#pragma unroll
    for (int i = 0; i < NODES; ++i) { a[i] = __expf(a[i] - m); den += a[i]; }
    const float r = 1.f / den;
    float* wr = &wt[wv][(j * 2 + h) * WT_S];
    *(float4*)&wr[0]  = make_float4(a[0]*r,  a[1]*r,  a[2]*r,  a[3]*r);
    *(float4*)&wr[4]  = make_float4(a[4]*r,  a[5]*r,  a[6]*r,  a[7]*r);
    *(float4*)&wr[8]  = make_float4(a[8]*r,  a[9]*r,  a[10]*r, a[11]*r);
    *(float2*)&wr[12] = make_float2(a[12]*r, a[13]*r);
  }

  // ---- agg1: head = lane>>5, feat = lane&31; shfl combine; ELU ----
  {
    const int h = lane >> 5, f5 = lane & 31;
    const float bb = b1[f5];
#pragma unroll 2
    for (int n = 0; n < NODES; ++n) {
      const float* wr = &wt[wv][(n * 2 + h) * WT_S];
      const float4 w0 = *(const float4*)&wr[0];
      const float4 w1 = *(const float4*)&wr[4];
      const float4 w2 = *(const float4*)&wr[8];
      const float2 w3 = *(const float2*)&wr[12];
      float o = w0.x*xcol[0] + w0.y*xcol[1] + w0.z*xcol[2] + w0.w*xcol[3]
              + w1.x*xcol[4] + w1.y*xcol[5] + w1.z*xcol[6] + w1.w*xcol[7]
              + w2.x*xcol[8] + w2.y*xcol[9] + w2.z*xcol[10] + w2.w*xcol[11]
              + w3.x*xcol[12] + w3.y*xcol[13];
      const float oo = __shfl_xor(o, 32);
      if (h == 0) {
        const float v = 0.5f * (o + oo) + bb;
        h1s[wv][n * H1_S + f5] = v > 0.f ? v : expm1f(v);
      }
    }
  }
  PHASE_FENCE();   // deflate liveness before GEMM2

  // ---- GEMM2: lane owns cols {lane, 64+lane}; weights already in regs ----
  float acc0[NODES], acc1[NODES];
#pragma unroll 2
  for (int n = 0; n < NODES; ++n) {
    const float4 v0 = *(const float4*)&h1s[wv][n * H1_S + 0];
    const float4 v1 = *(const float4*)&h1s[wv][n * H1_S + 4];
    const float4 v2 = *(const float4*)&h1s[wv][n * H1_S + 8];
    const float4 v3 = *(const float4*)&h1s[wv][n * H1_S + 12];
    const float4 v4 = *(const float4*)&h1s[wv][n * H1_S + 16];
    const float4 v5 = *(const float4*)&h1s[wv][n * H1_S + 20];
    const float4 v6 = *(const float4*)&h1s[wv][n * H1_S + 24];
    const float4 v7 = *(const float4*)&h1s[wv][n * H1_S + 28];
    acc0[n] = v0.x*w2r[0] + v0.y*w2r[1] + v0.z*w2r[2] + v0.w*w2r[3]
            + v1.x*w2r[4] + v1.y*w2r[5] + v1.z*w2r[6] + v1.w*w2r[7]
            + v2.x*w2r[8] + v2.y*w2r[9] + v2.z*w2r[10] + v2.w*w2r[11]
            + v3.x*w2r[12] + v3.y*w2r[13] + v3.z*w2r[14] + v3.w*w2r[15]
            + v4.x*w2r[16] + v4.y*w2r[17] + v4.z*w2r[18] + v4.w*w2r[19]
            + v5.x*w2r[20] + v5.y*w2r[21] + v5.z*w2r[22] + v5.w*w2r[23]
            + v6.x*w2r[24] + v6.y*w2r[25] + v6.z*w2r[26] + v6.w*w2r[27]
            + v7.x*w2r[28] + v7.y*w2r[29] + v7.z*w2r[30] + v7.w*w2r[31];
    acc1[n] = v0.x*w2r[32] + v0.y*w2r[33] + v0.z*w2r[34] + v0.w*w2r[35]
            + v1.x*w2r[36] + v1.y*w2r[37] + v1.z*w2r[38] + v1.w*w2r[39]
            + v2.x*w2r[40] + v2.y*w2r[41] + v2.z*w2r[42] + v2.w*w2r[43]
            + v3.x*w2r[44] + v3.y*w2r[45] + v3.z*w2r[46] + v3.w*w2r[47]
            + v4.x*w2r[48] + v4.y*w2r[49] + v4.z*w2r[50] + v4.w*w2r[51]
            + v5.x*w2r[52] + v5.y*w2r[53] + v5.z*w2r[54] + v5.w*w2r[55]
            + v6.x*w2r[56] + v6.y*w2r[57] + v6.z*w2r[58] + v6.w*w2r[59]
            + v7.x*w2r[60] + v7.y*w2r[61] + v7.z*w2r[62] + v7.w*w2r[63];
  }

  // ---- logits2 (56 lanes): h1 row . u2 row ----
  if (lane < 56) {
    const int n = lane >> 2, h = (lane >> 1) & 1, sd = lane & 1;
    const float* uu = uvec + (sd ? U_UD2 : U_US2) + h * HID1;
    float s = 0.f;
#pragma unroll
    for (int k4 = 0; k4 < 8; ++k4) {
      const float4 hv = *(const float4*)&h1s[wv][n * H1_S + k4 * 4];
      const float4 uv = *(const float4*)&uu[k4 * 4];
      s += hv.x * uv.x + hv.y * uv.y + hv.z * uv.z + hv.w * uv.w;
    }
    (sd ? ald : als)[wv][h * 16 + n] = s;
  }
  // ---- softmax2 (28 lanes) ----
  if (lane < NODES * 2) {
    const int j = lane >> 1, h = lane & 1;
    const float ad = ald[wv][h * 16 + j];
    const float4 A0 = *(const float4*)&als[wv][h * 16 + 0];
    const float4 A1 = *(const float4*)&als[wv][h * 16 + 4];
    const float4 A2 = *(const float4*)&als[wv][h * 16 + 8];
    const float2 A3 = *(const float2*)&als[wv][h * 16 + 12];
    float a[NODES] = {A0.x, A0.y, A0.z, A0.w, A1.x, A1.y, A1.z, A1.w,
                      A2.x, A2.y, A2.z, A2.w, A3.x, A3.y};
    float m = -1e30f;
#pragma unroll
    for (int i = 0; i < NODES; ++i) {
      float v = a[i] + ad;
      v = v > 0.f ? v : SLOPE * v;
      a[i] = v; m = fmaxf(m, v);
    }
    float den = 0.f;
#pragma unroll
    for (int i = 0; i < NODES; ++i) { a[i] = __expf(a[i] - m); den += a[i]; }
    const float r = 1.f / den;
    float* wr = &wt[wv][(j * 2 + h) * WT_S];
    *(float4*)&wr[0]  = make_float4(a[0]*r,  a[1]*r,  a[2]*r,  a[3]*r);
    *(float4*)&wr[4]  = make_float4(a[4]*r,  a[5]*r,  a[6]*r,  a[7]*r);
    *(float4*)&wr[8]  = make_float4(a[8]*r,  a[9]*r,  a[10]*r, a[11]*r);
    *(float2*)&wr[12] = make_float2(a[12]*r, a[13]*r);
  }

  // ---- agg2: lane-local for both heads ----
  {
    const float bb = b2[lane];
#pragma unroll 2
    for (int n = 0; n < NODES; ++n) {
      const float* wr0 = &wt[wv][(n * 2 + 0) * WT_S];
      const float* wr1 = &wt[wv][(n * 2 + 1) * WT_S];
      const float4 p0 = *(const float4*)&wr0[0];
      const float4 p1 = *(const float4*)&wr0[4];
      const float4 p2 = *(const float4*)&wr0[8];
      const float2 p3 = *(const float2*)&wr0[12];
      const float4 q0 = *(const float4*)&wr1[0];
      const float4 q1 = *(const float4*)&wr1[4];
      const float4 q2 = *(const float4*)&wr1[8];
      const float2 q3 = *(const float2*)&wr1[12];
      const float o0 = p0.x*acc0[0] + p0.y*acc0[1] + p0.z*acc0[2] + p0.w*acc0[3]
                     + p1.x*acc0[4] + p1.y*acc0[5] + p1.z*acc0[6] + p1.w*acc0[7]
                     + p2.x*acc0[8] + p2.y*acc0[9] + p2.z*acc0[10] + p2.w*acc0[11]
                     + p3.x*acc0[12] + p3.y*acc0[13];
      const float o1 = q0.x*acc1[0] + q0.y*acc1[1] + q0.z*acc1[2] + q0.w*acc1[3]
                     + q1.x*acc1[4] + q1.y*acc1[5] + q1.z*acc1[6] + q1.w*acc1[7]
                     + q2.x*acc1[8] + q2.y*acc1[9] + q2.z*acc1[10] + q2.w*acc1[11]
                     + q3.x*acc1[12] + q3.y*acc1[13];
      h2s[wv][n * H2_S + lane] = 0.5f * (o0 + o1) + bb;
    }
  }
  PHASE_FENCE();   // deflate liveness before MLP

  // ---- MLP1 (112 items; float4 h2 broadcasts, conflict-free k*68) ----
  for (int idx = lane; idx < NODES * 8; idx += 64) {
    const int k = idx >> 3, e = idx & 7;
    float acc = bf1[k * 8 + e];
#pragma unroll
    for (int f4 = 0; f4 < 16; ++f4) {
      const float4 hv = *(const float4*)&h2s[wv][k * H2_S + f4 * 4];
      acc += hv.x * Wf1[(k * HID2 + f4 * 4 + 0) * 8 + e]
           + hv.y * Wf1[(k * HID2 + f4 * 4 + 1) * 8 + e]
           + hv.z * Wf1[(k * HID2 + f4 * 4 + 2) * 8 + e]
           + hv.w * Wf1[(k * HID2 + f4 * 4 + 3) * 8 + e];
    }
    hhs[wv][idx] = fmaxf(acc, 0.f);
  }

  // ---- MLP2 (336 outputs; float4 hhs broadcasts) ----
  for (int idx = lane; idx < NODES * OUT_F; idx += 64) {
    const int k = idx / OUT_F, o = idx - k * OUT_F;
    const float4 h0 = *(const float4*)&hhs[wv][k * 8];
    const float4 h1 = *(const float4*)&hhs[wv][k * 8 + 4];
    float acc = bf2[k * OUT_F + o]
              + h0.x * Wf2[(k * 8 + 0) * OUT_F + o]
              + h0.y * Wf2[(k * 8 + 1) * OUT_F + o]
              + h0.z * Wf2[(k * 8 + 2) * OUT_F + o]
              + h0.w * Wf2[(k * 8 + 3) * OUT_F + o]
              + h1.x * Wf2[(k * 8 + 4) * OUT_F + o]
              + h1.y * Wf2[(k * 8 + 5) * OUT_F + o]
              + h1.z * Wf2[(k * 8 + 6) * OUT_F + o]
              + h1.w * Wf2[(k * 8 + 7) * OUT_F + o];
    out[(size_t)k * ngraphs * OUT_F + (size_t)gu * OUT_F + o] =
        1.f / (1.f + __expf(-acc));
  }
}

extern "C" void kernel_launch(void* const* d_in, const int* in_sizes, int n_in,
                              void* d_out, int out_size, void* d_ws, size_t ws_size,
                              hipStream_t stream) {
  const float* x      = (const float*)d_in[0];
  const float* y      = (const float*)d_in[1];
  // d_in[2] = edge_index, d_in[3] = batch : structure fixed, unused
  const float* W1     = (const float*)d_in[4];
  const float* a_src1 = (const float*)d_in[5];
  const float* a_dst1 = (const float*)d_in[6];
  const float* b1     = (const float*)d_in[7];
  const float* W2     = (const float*)d_in[8];
  const float* a_src2 = (const float*)d_in[9];
  const float* a_dst2 = (const float*)d_in[10];
  const float* b2     = (const float*)d_in[11];
  const float* Wf1    = (const float*)d_in[12];
  const float* bf1    = (const float*)d_in[13];
  const float* Wf2    = (const float*)d_in[14];
  const float* bf2    = (const float*)d_in[15];
  float* out = (float*)d_out;
  float* u   = (float*)d_ws;

  const int nnodes  = in_sizes[0] / IN_F;
  const int ngraphs = nnodes / NODES;
  const int nblocks = (ngraphs + GPB - 1) / GPB;

  hipLaunchKernelGGL(compute_uvecs, dim3(1), dim3(256), 0, stream,
                     W1, a_src1, a_dst1, W2, a_src2, a_dst2, u);
  hipLaunchKernelGGL(gnn_fused, dim3(nblocks), dim3(64 * GPB), 0, stream,
                     x, y, W1, b1, W2, b2, Wf1, bf1, Wf2, bf2, u, out, ngraphs);
}